// Round 6
// baseline (398.408 us; speedup 1.0000x reference)
//
#include <hip/hip_runtime.h>
#include <stdint.h>

typedef unsigned short u16;
typedef __bf16 bf16x8 __attribute__((ext_vector_type(8)));
typedef short s16x4 __attribute__((ext_vector_type(4)));
typedef float f32x4 __attribute__((ext_vector_type(4)));

typedef __attribute__((address_space(1))) void gvoid_t;
typedef __attribute__((address_space(3))) void lvoid_t;

struct alignas(16) U128 { uint32_t x, y, z, w; };
struct alignas(16) F128 { float x, y, z, w; };
struct alignas(8)  U64v { uint32_t x, y; };

__device__ __forceinline__ void gld16(const u16* g, u16* lds) {
  __builtin_amdgcn_global_load_lds((gvoid_t*)const_cast<u16*>(g),
                                   (lvoid_t*)lds, 16, 0, 0);
}

__device__ __forceinline__ u16 f2bf(float f) {
  uint32_t u = __builtin_bit_cast(uint32_t, f);
  u += 0x7FFFu + ((u >> 16) & 1u);   // RNE
  return (u16)(u >> 16);
}
__device__ __forceinline__ float bf2f(u16 h) {
  return __builtin_bit_cast(float, (uint32_t)h << 16);
}
__device__ __forceinline__ bf16x8 ldfrag(const u16* p) {
  U128 u = *reinterpret_cast<const U128*>(p);
  return __builtin_bit_cast(bf16x8, u);
}
// pack two f32 -> bf16x2 dword, round-half-up (values >= 0)
__device__ __forceinline__ uint32_t pkbf(float a, float b) {
  uint32_t ua = __builtin_bit_cast(uint32_t, a) + 0x8000u;
  uint32_t ub = __builtin_bit_cast(uint32_t, b) + 0x8000u;
  return (ua >> 16) | (ub & 0xFFFF0000u);
}

// raw v_exp_f32 (exp2). amdgcn builtins are callable unconditionally in HIP TUs
// (host pass parses them fine — proven by the MFMA builtins in this file).
__device__ __forceinline__ float EXP2(float x) { return __builtin_amdgcn_exp2f(x); }

// ---------------- fp32 -> bf16 convert (x) ----------------
__global__ void cvt_f32_bf16(const float* __restrict__ in, u16* __restrict__ out) {
  int i = (blockIdx.x * 256 + threadIdx.x) * 4;
  F128 v = *reinterpret_cast<const F128*>(in + i);
  U64v o;
  o.x = (uint32_t)f2bf(v.x) | ((uint32_t)f2bf(v.y) << 16);
  o.y = (uint32_t)f2bf(v.z) | ((uint32_t)f2bf(v.w) << 16);
  *reinterpret_cast<U64v*>(out + i) = o;
}

// ---------------- transpose + convert weights: W (K x N f32) -> Wt (N x K bf16) ----
__global__ void transpose_cvt(const float* __restrict__ W, u16* __restrict__ Wt,
                              int K, int N) {
  __shared__ float T[32][33];
  const int n0 = blockIdx.x * 32, k0 = blockIdx.y * 32;
  const int tid = threadIdx.x;
#pragma unroll
  for (int i = 0; i < 4; ++i) {
    int e = i * 256 + tid, r = e >> 5, c = e & 31;
    T[r][c] = W[(size_t)(k0 + r) * N + n0 + c];
  }
  __syncthreads();
#pragma unroll
  for (int i = 0; i < 4; ++i) {
    int e = i * 256 + tid, r = e >> 5, c = e & 31;
    Wt[(size_t)(n0 + r) * K + k0 + c] = f2bf(T[c][r]);
  }
}

// ---------------- GEMM: C[M,N] = A[M,K] * Bt[N,K]^T + bias  (m97-style) -------------
template <int BF16_OUT>
__global__ __launch_bounds__(256, 2)
void gemm_bt(const u16* __restrict__ A, const u16* __restrict__ Bt,
             const float* __restrict__ bias, void* __restrict__ C,
             int M, int N, int K) {
  __shared__ u16 As[128 * 32];
  __shared__ u16 Bs[128 * 32];
  const int tid = threadIdx.x;
  const int wave = tid >> 6, lane = tid & 63;
  const int quad = lane >> 4, l16 = lane & 15;
  const int m0 = blockIdx.y * 128, n0 = blockIdx.x * 128;
  const int wr = (wave & 1) * 64, wc = (wave >> 1) * 64;

  f32x4 acc[4][4];
#pragma unroll
  for (int i = 0; i < 4; ++i)
#pragma unroll
    for (int j = 0; j < 4; ++j) acc[i][j] = (f32x4){0.f, 0.f, 0.f, 0.f};

  for (int k0 = 0; k0 < K; k0 += 32) {
    __syncthreads();
#pragma unroll
    for (int j = 0; j < 2; ++j) {
      int c = (wave * 2 + j) * 64 + lane;
      int row = c >> 2, kq = c & 3;
      gld16(A + (size_t)(m0 + row) * K + k0 + kq * 8, &As[(wave * 2 + j) * 512]);
      gld16(Bt + (size_t)(n0 + row) * K + k0 + kq * 8, &Bs[(wave * 2 + j) * 512]);
    }
    __syncthreads();
    bf16x8 af[4], bfr[4];
#pragma unroll
    for (int rb = 0; rb < 4; ++rb) af[rb] = ldfrag(&As[(wr + rb * 16 + l16) * 32 + quad * 8]);
#pragma unroll
    for (int cb = 0; cb < 4; ++cb) bfr[cb] = ldfrag(&Bs[(wc + cb * 16 + l16) * 32 + quad * 8]);
#pragma unroll
    for (int rb = 0; rb < 4; ++rb)
#pragma unroll
      for (int cb = 0; cb < 4; ++cb)
        acc[rb][cb] = __builtin_amdgcn_mfma_f32_16x16x32_bf16(af[rb], bfr[cb], acc[rb][cb], 0, 0, 0);
  }
#pragma unroll
  for (int cb = 0; cb < 4; ++cb) {
    int col = n0 + wc + cb * 16 + l16;
    float bv = bias[col];
#pragma unroll
    for (int rb = 0; rb < 4; ++rb) {
#pragma unroll
      for (int r = 0; r < 4; ++r) {
        int row = m0 + wr + rb * 16 + quad * 4 + r;
        float v = acc[rb][cb][r] + bv;
        if constexpr (BF16_OUT)
          ((u16*)C)[(size_t)row * N + col] = f2bf(v);
        else
          ((float*)C)[(size_t)row * N + col] = v;
      }
    }
  }
}

// ---------------- RoPE + scatter into attention layouts ----------------------------
// Q gets pre-scaled by D^-0.5 * log2(e) so attn softmax runs in log2 domain.
__global__ void rope_scatter(const u16* __restrict__ qkvb,
                             const float* __restrict__ cosT, const float* __restrict__ sinT,
                             const int* __restrict__ nsp,
                             u16* __restrict__ Qo, u16* __restrict__ Ko, u16* __restrict__ Vto) {
  __shared__ float Vls[64][65];
  const int tid = threadIdx.x;
  const int t0 = blockIdx.x * 64, h = blockIdx.y, b = blockIdx.z;
  const int bh = b * 12 + h;
  const int num_special = nsp[0];
  const float QS = 0.125f * 1.4426950408889634f;  // D^-0.5 * log2e

#pragma unroll
  for (int s = 0; s < 2; ++s) {  // 0: q, 1: k
    const int base_col = s * 768 + h * 64;
    u16* outp = s ? Ko : Qo;
    const float qs = s ? 1.0f : QS;
#pragma unroll
    for (int i = 0; i < 8; ++i) {
      int pid = i * 256 + tid;
      int t = pid >> 5, dp = pid & 31;
      int n = t0 + t;
      size_t m = (size_t)b * 2048 + n;
      float x1 = bf2f(qkvb[m * 2304 + base_col + dp]);
      float x2 = bf2f(qkvb[m * 2304 + base_col + dp + 32]);
      float o1, o2;
      if (n < num_special) {
        o1 = x1; o2 = x2;
      } else {
        int ns = n - num_special;
        float c1 = cosT[ns * 64 + dp],      s1 = sinT[ns * 64 + dp];
        float c2 = cosT[ns * 64 + dp + 32], s2 = sinT[ns * 64 + dp + 32];
        o1 = x1 * c1 - x2 * s1;
        o2 = x2 * c2 + x1 * s2;
      }
      size_t ob = ((size_t)bh * 2048 + n) * 64;
      outp[ob + dp] = f2bf(o1 * qs);
      outp[ob + dp + 32] = f2bf(o2 * qs);
    }
  }
#pragma unroll
  for (int i = 0; i < 16; ++i) {
    int e = i * 256 + tid, t = e >> 6, d = e & 63;
    size_t m = (size_t)b * 2048 + t0 + t;
    Vls[t][d] = bf2f(qkvb[m * 2304 + 1536 + h * 64 + d]);
  }
  __syncthreads();
#pragma unroll
  for (int i = 0; i < 16; ++i) {
    int e = i * 256 + tid, d = e >> 6, t = e & 63;
    Vto[((size_t)bh * 64 + d) * 2048 + t0 + t] = f2bf(Vls[t][d]);
  }
}

// ---------------- flash attention (S^T form, no-max softmax, reg-prefetch) ----------
// 1D grid 1536 = qt*48 + bh: all 32 qt-blocks of one bh land on XCD bh%8
// (round-robin dispatch, 48%8==0) -> K/V stay resident in that XCD's L2.
// Wave owns 16 q rows; lane holds S^T[key=kb*16+quad*4+r][query=l16]; exp'd
// values are directly the A-frag of the 16x16x16 PV MFMA. No-max softmax is
// exact here (|log2-scores| < ~10). K/V tiles for kt+1 are loaded into VGPRs
// during kt's compute and written to LDS next iteration.
__global__ __launch_bounds__(256, 6)
void attn(const u16* __restrict__ Q, const u16* __restrict__ Kg,
          const u16* __restrict__ Vt, u16* __restrict__ Out) {
  __shared__ u16 smem[2 * 64 * 72];   // 18432 B: [Ks | Vs]; Qs overlays Ks
  u16* Ks = smem;
  u16* Vs = smem + 64 * 72;
  u16* Qs = smem;
  const int tid = threadIdx.x;
  const int wave = tid >> 6, lane = tid & 63;
  const int quad = lane >> 4, l16 = lane & 15;
  const int idx = blockIdx.x;
  const int bh = idx % 48, qt = idx / 48;
  const int b = bh / 12, h = bh % 12;
  const u16* Qb = Q + (size_t)bh * 2048 * 64;
  const u16* Kb = Kg + (size_t)bh * 2048 * 64;
  const u16* Vb = Vt + (size_t)bh * 64 * 2048;

  // staging geometry: chunk c = j*256+tid; row=c>>3 (0..63), kq=c&7
  const int c0 = tid, c1 = 256 + tid;
  const int r0 = c0 >> 3, q0 = c0 & 7;
  const int r1 = c1 >> 3, q1 = c1 & 7;
  const u16* gk0 = Kb + r0 * 64 + q0 * 8;
  const u16* gk1 = Kb + r1 * 64 + q1 * 8;
  const u16* gv0 = Vb + (size_t)r0 * 2048 + q0 * 8;
  const u16* gv1 = Vb + (size_t)r1 * 2048 + q1 * 8;
  u16* lk0 = &Ks[r0 * 72 + q0 * 8];
  u16* lk1 = &Ks[r1 * 72 + q1 * 8];
  u16* lv0 = &Vs[r0 * 72 + q0 * 8];
  u16* lv1 = &Vs[r1 * 72 + q1 * 8];

  // Q tile -> LDS (overlaying Ks), hoist Q frags
  *(U128*)&Qs[r0 * 72 + q0 * 8] = *(const U128*)(Qb + (size_t)(qt * 64 + r0) * 64 + q0 * 8);
  *(U128*)&Qs[r1 * 72 + q1 * 8] = *(const U128*)(Qb + (size_t)(qt * 64 + r1) * 64 + q1 * 8);
  __syncthreads();
  bf16x8 qf0 = ldfrag(&Qs[(wave * 16 + l16) * 72 + quad * 8]);
  bf16x8 qf1 = ldfrag(&Qs[(wave * 16 + l16) * 72 + quad * 8 + 32]);

  // prefetch kt=0 tiles into regs
  U128 pk0 = *(const U128*)gk0, pk1 = *(const U128*)gk1;
  U128 pv0 = *(const U128*)gv0, pv1 = *(const U128*)gv1;

  f32x4 ao[4];
#pragma unroll
  for (int db = 0; db < 4; ++db) ao[db] = (f32x4){0.f, 0.f, 0.f, 0.f};
  float lsum = 0.f;  // per-lane partial; reduced in epilogue

  for (int kt = 0; kt < 32; ++kt) {
    __syncthreads();   // prior-iter LDS reads (and qf reads at kt=0) done
    *(U128*)lk0 = pk0; *(U128*)lk1 = pk1;
    *(U128*)lv0 = pv0; *(U128*)lv1 = pv1;
    __syncthreads();

    // issue kt+1 global loads now — they drain during the MFMA section
    if (kt < 31) {
      gk0 += 4096; gk1 += 4096; gv0 += 64; gv1 += 64;
      pk0 = *(const U128*)gk0; pk1 = *(const U128*)gk1;
      pv0 = *(const U128*)gv0; pv1 = *(const U128*)gv1;
    }

    // S^T (log2 domain; scale*log2e folded into Q)
    f32x4 st[4];
#pragma unroll
    for (int kb = 0; kb < 4; ++kb) st[kb] = (f32x4){0.f, 0.f, 0.f, 0.f};
#pragma unroll
    for (int kb = 0; kb < 4; ++kb) {
      bf16x8 k0 = ldfrag(&Ks[(kb * 16 + l16) * 72 + quad * 8]);
      bf16x8 k1 = ldfrag(&Ks[(kb * 16 + l16) * 72 + quad * 8 + 32]);
      st[kb] = __builtin_amdgcn_mfma_f32_16x16x32_bf16(k0, qf0, st[kb], 0, 0, 0);
      st[kb] = __builtin_amdgcn_mfma_f32_16x16x32_bf16(k1, qf1, st[kb], 0, 0, 0);
    }

    // p = exp2(s) (single v_exp_f32 each); per-lane partial sum; pack to A-frags
    s16x4 pf[4];
#pragma unroll
    for (int kb = 0; kb < 4; ++kb) {
      float p0 = EXP2(st[kb][0]);
      float p1 = EXP2(st[kb][1]);
      float p2 = EXP2(st[kb][2]);
      float p3 = EXP2(st[kb][3]);
      lsum += (p0 + p1) + (p2 + p3);
      U64v pd;
      pd.x = pkbf(p0, p1);
      pd.y = pkbf(p2, p3);
      pf[kb] = __builtin_bit_cast(s16x4, pd);
    }

    // O += P V (no rescale)
#pragma unroll
    for (int db = 0; db < 4; ++db) {
      f32x4 t = ao[db];
#pragma unroll
      for (int kb = 0; kb < 4; ++kb) {
        s16x4 vf = __builtin_bit_cast(s16x4,
            *(const U64v*)&Vs[(db * 16 + l16) * 72 + kb * 16 + quad * 4]);
        t = __builtin_amdgcn_mfma_f32_16x16x16bf16_1k(pf[kb], vf, t, 0, 0, 0);
      }
      ao[db] = t;
    }
  }

  // total sum for query l16 across the 4 quads, then per-row reciprocal
  lsum += __shfl_xor(lsum, 16, 64);
  lsum += __shfl_xor(lsum, 32, 64);
  float inv[4];
#pragma unroll
  for (int r = 0; r < 4; ++r)
    inv[r] = 1.0f / __shfl(lsum, quad * 4 + r, 64);
#pragma unroll
  for (int db = 0; db < 4; ++db)
#pragma unroll
    for (int r = 0; r < 4; ++r) {
      int n = qt * 64 + wave * 16 + quad * 4 + r;
      size_t m = (size_t)b * 2048 + n;
      Out[m * 768 + h * 64 + db * 16 + l16] = f2bf(ao[db][r] * inv[r]);
    }
}

extern "C" void kernel_launch(void* const* d_in, const int* in_sizes, int n_in,
                              void* d_out, int out_size, void* d_ws, size_t ws_size,
                              hipStream_t stream) {
  (void)in_sizes; (void)n_in; (void)out_size; (void)ws_size;
  const float* x        = (const float*)d_in[0];
  const float* rope_cos = (const float*)d_in[1];
  const float* rope_sin = (const float*)d_in[2];
  const float* W_qkv    = (const float*)d_in[3];
  const float* b_qkv    = (const float*)d_in[4];
  const float* W_proj   = (const float*)d_in[5];
  const float* b_proj   = (const float*)d_in[6];
  const int*   nsp      = (const int*)d_in[7];
  float* out = (float*)d_out;

  char* ws = (char*)d_ws;
  u16* Xb   = (u16*)(ws);
  u16* Wqkt = (u16*)(ws + 12582912);
  u16* Wpt  = (u16*)(ws + 16121856);
  u16* qkvb = (u16*)(ws + 17301504);
  u16* Qb   = (u16*)(ws + 55050240);
  u16* Kb   = (u16*)(ws + 67633152);
  u16* Vtb  = (u16*)(ws + 80216064);
  u16* att  = (u16*)(ws + 92798976);

  cvt_f32_bf16<<<6144, 256, 0, stream>>>(x, Xb);
  transpose_cvt<<<dim3(72, 24), 256, 0, stream>>>(W_qkv, Wqkt, 768, 2304);
  transpose_cvt<<<dim3(24, 24), 256, 0, stream>>>(W_proj, Wpt, 768, 768);
  gemm_bt<1><<<dim3(18, 64), 256, 0, stream>>>(Xb, Wqkt, b_qkv, qkvb, 8192, 2304, 768);
  rope_scatter<<<dim3(32, 12, 4), 256, 0, stream>>>(qkvb, rope_cos, rope_sin, nsp, Qb, Kb, Vtb);
  attn<<<1536, 256, 0, stream>>>(Qb, Kb, Vtb, att);
  gemm_bt<0><<<dim3(6, 64), 256, 0, stream>>>(att, Wpt, b_proj, out, 8192, 768, 768);
}

// Round 7
// 283.345 us; speedup vs baseline: 1.4061x; 1.4061x over previous
//
#include <hip/hip_runtime.h>
#include <stdint.h>

typedef unsigned short u16;
typedef __bf16 bf16x8 __attribute__((ext_vector_type(8)));
typedef short s16x4 __attribute__((ext_vector_type(4)));
typedef float f32x4 __attribute__((ext_vector_type(4)));

typedef __attribute__((address_space(1))) void gvoid_t;
typedef __attribute__((address_space(3))) void lvoid_t;

struct alignas(16) U128 { uint32_t x, y, z, w; };
struct alignas(16) F128 { float x, y, z, w; };
struct alignas(8)  U64v { uint32_t x, y; };

__device__ __forceinline__ void gld16(const u16* g, u16* lds) {
  __builtin_amdgcn_global_load_lds((gvoid_t*)const_cast<u16*>(g),
                                   (lvoid_t*)lds, 16, 0, 0);
}

__device__ __forceinline__ u16 f2bf(float f) {
  uint32_t u = __builtin_bit_cast(uint32_t, f);
  u += 0x7FFFu + ((u >> 16) & 1u);   // RNE
  return (u16)(u >> 16);
}
__device__ __forceinline__ float bf2f(u16 h) {
  return __builtin_bit_cast(float, (uint32_t)h << 16);
}
__device__ __forceinline__ bf16x8 ldfrag(const u16* p) {
  U128 u = *reinterpret_cast<const U128*>(p);
  return __builtin_bit_cast(bf16x8, u);
}
// pack two f32 -> bf16x2 dword, round-half-up (values >= 0)
__device__ __forceinline__ uint32_t pkbf(float a, float b) {
  uint32_t ua = __builtin_bit_cast(uint32_t, a) + 0x8000u;
  uint32_t ub = __builtin_bit_cast(uint32_t, b) + 0x8000u;
  return (ua >> 16) | (ub & 0xFFFF0000u);
}

// raw v_exp_f32 (exp2) — scores bounded (|s|<~10), no denormal concerns
__device__ __forceinline__ float EXP2(float x) { return __builtin_amdgcn_exp2f(x); }

// ---------------- fp32 -> bf16 convert (x) ----------------
__global__ void cvt_f32_bf16(const float* __restrict__ in, u16* __restrict__ out) {
  int i = (blockIdx.x * 256 + threadIdx.x) * 4;
  F128 v = *reinterpret_cast<const F128*>(in + i);
  U64v o;
  o.x = (uint32_t)f2bf(v.x) | ((uint32_t)f2bf(v.y) << 16);
  o.y = (uint32_t)f2bf(v.z) | ((uint32_t)f2bf(v.w) << 16);
  *reinterpret_cast<U64v*>(out + i) = o;
}

// ---------------- transpose + convert weights: W (K x N f32) -> Wt (N x K bf16) ----
__global__ void transpose_cvt(const float* __restrict__ W, u16* __restrict__ Wt,
                              int K, int N) {
  __shared__ float T[32][33];
  const int n0 = blockIdx.x * 32, k0 = blockIdx.y * 32;
  const int tid = threadIdx.x;
#pragma unroll
  for (int i = 0; i < 4; ++i) {
    int e = i * 256 + tid, r = e >> 5, c = e & 31;
    T[r][c] = W[(size_t)(k0 + r) * N + n0 + c];
  }
  __syncthreads();
#pragma unroll
  for (int i = 0; i < 4; ++i) {
    int e = i * 256 + tid, r = e >> 5, c = e & 31;
    Wt[(size_t)(n0 + r) * K + k0 + c] = f2bf(T[c][r]);
  }
}

// ---------------- GEMM: C[M,N] = A[M,K] * Bt[N,K]^T + bias  (m97-style) -------------
template <int BF16_OUT>
__global__ __launch_bounds__(256, 2)
void gemm_bt(const u16* __restrict__ A, const u16* __restrict__ Bt,
             const float* __restrict__ bias, void* __restrict__ C,
             int M, int N, int K) {
  __shared__ u16 As[128 * 32];
  __shared__ u16 Bs[128 * 32];
  const int tid = threadIdx.x;
  const int wave = tid >> 6, lane = tid & 63;
  const int quad = lane >> 4, l16 = lane & 15;
  const int m0 = blockIdx.y * 128, n0 = blockIdx.x * 128;
  const int wr = (wave & 1) * 64, wc = (wave >> 1) * 64;

  f32x4 acc[4][4];
#pragma unroll
  for (int i = 0; i < 4; ++i)
#pragma unroll
    for (int j = 0; j < 4; ++j) acc[i][j] = (f32x4){0.f, 0.f, 0.f, 0.f};

  for (int k0 = 0; k0 < K; k0 += 32) {
    __syncthreads();
#pragma unroll
    for (int j = 0; j < 2; ++j) {
      int c = (wave * 2 + j) * 64 + lane;
      int row = c >> 2, kq = c & 3;
      gld16(A + (size_t)(m0 + row) * K + k0 + kq * 8, &As[(wave * 2 + j) * 512]);
      gld16(Bt + (size_t)(n0 + row) * K + k0 + kq * 8, &Bs[(wave * 2 + j) * 512]);
    }
    __syncthreads();
    bf16x8 af[4], bfr[4];
#pragma unroll
    for (int rb = 0; rb < 4; ++rb) af[rb] = ldfrag(&As[(wr + rb * 16 + l16) * 32 + quad * 8]);
#pragma unroll
    for (int cb = 0; cb < 4; ++cb) bfr[cb] = ldfrag(&Bs[(wc + cb * 16 + l16) * 32 + quad * 8]);
#pragma unroll
    for (int rb = 0; rb < 4; ++rb)
#pragma unroll
      for (int cb = 0; cb < 4; ++cb)
        acc[rb][cb] = __builtin_amdgcn_mfma_f32_16x16x32_bf16(af[rb], bfr[cb], acc[rb][cb], 0, 0, 0);
  }
#pragma unroll
  for (int cb = 0; cb < 4; ++cb) {
    int col = n0 + wc + cb * 16 + l16;
    float bv = bias[col];
#pragma unroll
    for (int rb = 0; rb < 4; ++rb) {
#pragma unroll
      for (int r = 0; r < 4; ++r) {
        int row = m0 + wr + rb * 16 + quad * 4 + r;
        float v = acc[rb][cb][r] + bv;
        if constexpr (BF16_OUT)
          ((u16*)C)[(size_t)row * N + col] = f2bf(v);
        else
          ((float*)C)[(size_t)row * N + col] = v;
      }
    }
  }
}

// ---------------- RoPE + scatter into attention layouts ----------------------------
// Q gets pre-scaled by D^-0.5 * log2(e) so attn softmax runs in log2 domain.
__global__ void rope_scatter(const u16* __restrict__ qkvb,
                             const float* __restrict__ cosT, const float* __restrict__ sinT,
                             const int* __restrict__ nsp,
                             u16* __restrict__ Qo, u16* __restrict__ Ko, u16* __restrict__ Vto) {
  __shared__ float Vls[64][65];
  const int tid = threadIdx.x;
  const int t0 = blockIdx.x * 64, h = blockIdx.y, b = blockIdx.z;
  const int bh = b * 12 + h;
  const int num_special = nsp[0];
  const float QS = 0.125f * 1.4426950408889634f;  // D^-0.5 * log2e

#pragma unroll
  for (int s = 0; s < 2; ++s) {  // 0: q, 1: k
    const int base_col = s * 768 + h * 64;
    u16* outp = s ? Ko : Qo;
    const float qs = s ? 1.0f : QS;
#pragma unroll
    for (int i = 0; i < 8; ++i) {
      int pid = i * 256 + tid;
      int t = pid >> 5, dp = pid & 31;
      int n = t0 + t;
      size_t m = (size_t)b * 2048 + n;
      float x1 = bf2f(qkvb[m * 2304 + base_col + dp]);
      float x2 = bf2f(qkvb[m * 2304 + base_col + dp + 32]);
      float o1, o2;
      if (n < num_special) {
        o1 = x1; o2 = x2;
      } else {
        int ns = n - num_special;
        float c1 = cosT[ns * 64 + dp],      s1 = sinT[ns * 64 + dp];
        float c2 = cosT[ns * 64 + dp + 32], s2 = sinT[ns * 64 + dp + 32];
        o1 = x1 * c1 - x2 * s1;
        o2 = x2 * c2 + x1 * s2;
      }
      size_t ob = ((size_t)bh * 2048 + n) * 64;
      outp[ob + dp] = f2bf(o1 * qs);
      outp[ob + dp + 32] = f2bf(o2 * qs);
    }
  }
#pragma unroll
  for (int i = 0; i < 16; ++i) {
    int e = i * 256 + tid, t = e >> 6, d = e & 63;
    size_t m = (size_t)b * 2048 + t0 + t;
    Vls[t][d] = bf2f(qkvb[m * 2304 + 1536 + h * 64 + d]);
  }
  __syncthreads();
#pragma unroll
  for (int i = 0; i < 16; ++i) {
    int e = i * 256 + tid, d = e >> 6, t = e & 63;
    Vto[((size_t)bh * 64 + d) * 2048 + t0 + t] = f2bf(Vls[t][d]);
  }
}

// ---------------- flash attention (S^T form, no-max softmax, XCD-local grid) --------
// 1D grid 1536 = qt*48 + bh: all 32 qt-blocks of one bh land on XCD bh%8
// (round-robin dispatch, 48%8==0) -> that bh's 512 KB K/V stays L2-resident.
// Wave owns 16 q rows; lane holds S^T[key=kb*16+quad*4+r][query=l16]; exp'd
// values are directly the A-frag of the 16x16x16 PV MFMA. No-max softmax is
// exact here (|log2-scores| < ~10). Staging = load->immediate LDS store (NO
// cross-section register prefetch: that spilled 2xU128/lane/iter = 400 MB
// scratch writes in R6).
__global__ __launch_bounds__(256, 6)
void attn(const u16* __restrict__ Q, const u16* __restrict__ Kg,
          const u16* __restrict__ Vt, u16* __restrict__ Out) {
  __shared__ u16 smem[2 * 64 * 72];   // 18432 B: [Ks | Vs]; Qs overlays Ks
  u16* Ks = smem;
  u16* Vs = smem + 64 * 72;
  u16* Qs = smem;
  const int tid = threadIdx.x;
  const int wave = tid >> 6, lane = tid & 63;
  const int quad = lane >> 4, l16 = lane & 15;
  const int idx = blockIdx.x;
  const int bh = idx % 48, qt = idx / 48;
  const int b = bh / 12, h = bh % 12;
  const u16* Qb = Q + (size_t)bh * 2048 * 64;
  const u16* Kb = Kg + (size_t)bh * 2048 * 64;
  const u16* Vb = Vt + (size_t)bh * 64 * 2048;

#pragma unroll
  for (int j = 0; j < 2; ++j) {
    int c = j * 256 + tid;
    int row = c >> 3, kq = c & 7;
    *(U128*)&Qs[row * 72 + kq * 8] =
        *(const U128*)(Qb + (size_t)(qt * 64 + row) * 64 + kq * 8);
  }
  __syncthreads();
  bf16x8 qf0 = ldfrag(&Qs[(wave * 16 + l16) * 72 + quad * 8]);
  bf16x8 qf1 = ldfrag(&Qs[(wave * 16 + l16) * 72 + quad * 8 + 32]);

  f32x4 ao[4];
#pragma unroll
  for (int db = 0; db < 4; ++db) ao[db] = (f32x4){0.f, 0.f, 0.f, 0.f};
  float lsum = 0.f;  // per-lane partial; reduced in epilogue

  for (int kt = 0; kt < 32; ++kt) {
    __syncthreads();   // prior-iter LDS reads (and qf reads at kt=0) done
#pragma unroll
    for (int j = 0; j < 2; ++j) {
      int c = j * 256 + tid;
      int row = c >> 3, kq = c & 7;
      *(U128*)&Ks[row * 72 + kq * 8] =
          *(const U128*)(Kb + (size_t)(kt * 64 + row) * 64 + kq * 8);
      *(U128*)&Vs[row * 72 + kq * 8] =
          *(const U128*)(Vb + (size_t)row * 2048 + kt * 64 + kq * 8);
    }
    __syncthreads();

    // S^T (log2 domain; scale*log2e folded into Q)
    f32x4 st[4];
#pragma unroll
    for (int kb = 0; kb < 4; ++kb) st[kb] = (f32x4){0.f, 0.f, 0.f, 0.f};
#pragma unroll
    for (int kb = 0; kb < 4; ++kb) {
      bf16x8 k0 = ldfrag(&Ks[(kb * 16 + l16) * 72 + quad * 8]);
      bf16x8 k1 = ldfrag(&Ks[(kb * 16 + l16) * 72 + quad * 8 + 32]);
      st[kb] = __builtin_amdgcn_mfma_f32_16x16x32_bf16(k0, qf0, st[kb], 0, 0, 0);
      st[kb] = __builtin_amdgcn_mfma_f32_16x16x32_bf16(k1, qf1, st[kb], 0, 0, 0);
    }

    // p = exp2(s) (raw v_exp_f32); per-lane partial sum; pack to A-frags
    s16x4 pf[4];
#pragma unroll
    for (int kb = 0; kb < 4; ++kb) {
      float p0 = EXP2(st[kb][0]);
      float p1 = EXP2(st[kb][1]);
      float p2 = EXP2(st[kb][2]);
      float p3 = EXP2(st[kb][3]);
      lsum += (p0 + p1) + (p2 + p3);
      U64v pd;
      pd.x = pkbf(p0, p1);
      pd.y = pkbf(p2, p3);
      pf[kb] = __builtin_bit_cast(s16x4, pd);
    }

    // O += P V (no rescale)
#pragma unroll
    for (int db = 0; db < 4; ++db) {
      f32x4 t = ao[db];
#pragma unroll
      for (int kb = 0; kb < 4; ++kb) {
        s16x4 vf = __builtin_bit_cast(s16x4,
            *(const U64v*)&Vs[(db * 16 + l16) * 72 + kb * 16 + quad * 4]);
        t = __builtin_amdgcn_mfma_f32_16x16x16bf16_1k(pf[kb], vf, t, 0, 0, 0);
      }
      ao[db] = t;
    }
  }

  // total sum for query l16 across the 4 quads, then per-row reciprocal
  lsum += __shfl_xor(lsum, 16, 64);
  lsum += __shfl_xor(lsum, 32, 64);
  float inv[4];
#pragma unroll
  for (int r = 0; r < 4; ++r)
    inv[r] = 1.0f / __shfl(lsum, quad * 4 + r, 64);
#pragma unroll
  for (int db = 0; db < 4; ++db)
#pragma unroll
    for (int r = 0; r < 4; ++r) {
      int n = qt * 64 + wave * 16 + quad * 4 + r;
      size_t m = (size_t)b * 2048 + n;
      Out[m * 768 + h * 64 + db * 16 + l16] = f2bf(ao[db][r] * inv[r]);
    }
}

extern "C" void kernel_launch(void* const* d_in, const int* in_sizes, int n_in,
                              void* d_out, int out_size, void* d_ws, size_t ws_size,
                              hipStream_t stream) {
  (void)in_sizes; (void)n_in; (void)out_size; (void)ws_size;
  const float* x        = (const float*)d_in[0];
  const float* rope_cos = (const float*)d_in[1];
  const float* rope_sin = (const float*)d_in[2];
  const float* W_qkv    = (const float*)d_in[3];
  const float* b_qkv    = (const float*)d_in[4];
  const float* W_proj   = (const float*)d_in[5];
  const float* b_proj   = (const float*)d_in[6];
  const int*   nsp      = (const int*)d_in[7];
  float* out = (float*)d_out;

  char* ws = (char*)d_ws;
  u16* Xb   = (u16*)(ws);
  u16* Wqkt = (u16*)(ws + 12582912);
  u16* Wpt  = (u16*)(ws + 16121856);
  u16* qkvb = (u16*)(ws + 17301504);
  u16* Qb   = (u16*)(ws + 55050240);
  u16* Kb   = (u16*)(ws + 67633152);
  u16* Vtb  = (u16*)(ws + 80216064);
  u16* att  = (u16*)(ws + 92798976);

  cvt_f32_bf16<<<6144, 256, 0, stream>>>(x, Xb);
  transpose_cvt<<<dim3(72, 24), 256, 0, stream>>>(W_qkv, Wqkt, 768, 2304);
  transpose_cvt<<<dim3(24, 24), 256, 0, stream>>>(W_proj, Wpt, 768, 768);
  gemm_bt<1><<<dim3(18, 64), 256, 0, stream>>>(Xb, Wqkt, b_qkv, qkvb, 8192, 2304, 768);
  rope_scatter<<<dim3(32, 12, 4), 256, 0, stream>>>(qkvb, rope_cos, rope_sin, nsp, Qb, Kb, Vtb);
  attn<<<1536, 256, 0, stream>>>(Qb, Kb, Vtb, att);
  gemm_bt<0><<<dim3(6, 64), 256, 0, stream>>>(att, Wpt, b_proj, out, 8192, 768, 768);
}

// Round 8
// 259.545 us; speedup vs baseline: 1.5350x; 1.0917x over previous
//
#include <hip/hip_runtime.h>
#include <stdint.h>

typedef unsigned short u16;
typedef __bf16 bf16x8 __attribute__((ext_vector_type(8)));
typedef short s16x4 __attribute__((ext_vector_type(4)));
typedef float f32x4 __attribute__((ext_vector_type(4)));

typedef __attribute__((address_space(1))) void gvoid_t;
typedef __attribute__((address_space(3))) void lvoid_t;

struct alignas(16) U128 { uint32_t x, y, z, w; };
struct alignas(16) F128 { float x, y, z, w; };
struct alignas(8)  U64v { uint32_t x, y; };

__device__ __forceinline__ void gld16(const u16* g, u16* lds) {
  __builtin_amdgcn_global_load_lds((gvoid_t*)const_cast<u16*>(g),
                                   (lvoid_t*)lds, 16, 0, 0);
}

__device__ __forceinline__ u16 f2bf(float f) {
  uint32_t u = __builtin_bit_cast(uint32_t, f);
  u += 0x7FFFu + ((u >> 16) & 1u);   // RNE
  return (u16)(u >> 16);
}
__device__ __forceinline__ float bf2f(u16 h) {
  return __builtin_bit_cast(float, (uint32_t)h << 16);
}
__device__ __forceinline__ bf16x8 ldfrag(const u16* p) {
  U128 u = *reinterpret_cast<const U128*>(p);
  return __builtin_bit_cast(bf16x8, u);
}
// pack two f32 -> bf16x2 dword, round-half-up (values >= 0)
__device__ __forceinline__ uint32_t pkbf(float a, float b) {
  uint32_t ua = __builtin_bit_cast(uint32_t, a) + 0x8000u;
  uint32_t ub = __builtin_bit_cast(uint32_t, b) + 0x8000u;
  return (ua >> 16) | (ub & 0xFFFF0000u);
}

// raw v_exp_f32 (exp2) — scores bounded (|s|<~10), no denormal concerns
__device__ __forceinline__ float EXP2(float x) { return __builtin_amdgcn_exp2f(x); }

// ---------------- fp32 -> bf16 convert (x) ----------------
__global__ void cvt_f32_bf16(const float* __restrict__ in, u16* __restrict__ out) {
  int i = (blockIdx.x * 256 + threadIdx.x) * 4;
  F128 v = *reinterpret_cast<const F128*>(in + i);
  U64v o;
  o.x = (uint32_t)f2bf(v.x) | ((uint32_t)f2bf(v.y) << 16);
  o.y = (uint32_t)f2bf(v.z) | ((uint32_t)f2bf(v.w) << 16);
  *reinterpret_cast<U64v*>(out + i) = o;
}

// ---------------- transpose + convert weights: W (K x N f32) -> Wt (N x K bf16) ----
__global__ void transpose_cvt(const float* __restrict__ W, u16* __restrict__ Wt,
                              int K, int N) {
  __shared__ float T[32][33];
  const int n0 = blockIdx.x * 32, k0 = blockIdx.y * 32;
  const int tid = threadIdx.x;
#pragma unroll
  for (int i = 0; i < 4; ++i) {
    int e = i * 256 + tid, r = e >> 5, c = e & 31;
    T[r][c] = W[(size_t)(k0 + r) * N + n0 + c];
  }
  __syncthreads();
#pragma unroll
  for (int i = 0; i < 4; ++i) {
    int e = i * 256 + tid, r = e >> 5, c = e & 31;
    Wt[(size_t)(n0 + r) * K + k0 + c] = f2bf(T[c][r]);
  }
}

// ---------------- GEMM: C[M,N] = A[M,K] * Bt[N,K]^T + bias  (m97-style) -------------
template <int BF16_OUT>
__global__ __launch_bounds__(256, 2)
void gemm_bt(const u16* __restrict__ A, const u16* __restrict__ Bt,
             const float* __restrict__ bias, void* __restrict__ C,
             int M, int N, int K) {
  __shared__ u16 As[128 * 32];
  __shared__ u16 Bs[128 * 32];
  const int tid = threadIdx.x;
  const int wave = tid >> 6, lane = tid & 63;
  const int quad = lane >> 4, l16 = lane & 15;
  const int m0 = blockIdx.y * 128, n0 = blockIdx.x * 128;
  const int wr = (wave & 1) * 64, wc = (wave >> 1) * 64;

  f32x4 acc[4][4];
#pragma unroll
  for (int i = 0; i < 4; ++i)
#pragma unroll
    for (int j = 0; j < 4; ++j) acc[i][j] = (f32x4){0.f, 0.f, 0.f, 0.f};

  for (int k0 = 0; k0 < K; k0 += 32) {
    __syncthreads();
#pragma unroll
    for (int j = 0; j < 2; ++j) {
      int c = (wave * 2 + j) * 64 + lane;
      int row = c >> 2, kq = c & 3;
      gld16(A + (size_t)(m0 + row) * K + k0 + kq * 8, &As[(wave * 2 + j) * 512]);
      gld16(Bt + (size_t)(n0 + row) * K + k0 + kq * 8, &Bs[(wave * 2 + j) * 512]);
    }
    __syncthreads();
    bf16x8 af[4], bfr[4];
#pragma unroll
    for (int rb = 0; rb < 4; ++rb) af[rb] = ldfrag(&As[(wr + rb * 16 + l16) * 32 + quad * 8]);
#pragma unroll
    for (int cb = 0; cb < 4; ++cb) bfr[cb] = ldfrag(&Bs[(wc + cb * 16 + l16) * 32 + quad * 8]);
#pragma unroll
    for (int rb = 0; rb < 4; ++rb)
#pragma unroll
      for (int cb = 0; cb < 4; ++cb)
        acc[rb][cb] = __builtin_amdgcn_mfma_f32_16x16x32_bf16(af[rb], bfr[cb], acc[rb][cb], 0, 0, 0);
  }
#pragma unroll
  for (int cb = 0; cb < 4; ++cb) {
    int col = n0 + wc + cb * 16 + l16;
    float bv = bias[col];
#pragma unroll
    for (int rb = 0; rb < 4; ++rb) {
#pragma unroll
      for (int r = 0; r < 4; ++r) {
        int row = m0 + wr + rb * 16 + quad * 4 + r;
        float v = acc[rb][cb][r] + bv;
        if constexpr (BF16_OUT)
          ((u16*)C)[(size_t)row * N + col] = f2bf(v);
        else
          ((float*)C)[(size_t)row * N + col] = v;
      }
    }
  }
}

// ---------------- RoPE + scatter into attention layouts ----------------------------
// Q gets pre-scaled by D^-0.5 * log2(e) so attn softmax runs in log2 domain.
__global__ void rope_scatter(const u16* __restrict__ qkvb,
                             const float* __restrict__ cosT, const float* __restrict__ sinT,
                             const int* __restrict__ nsp,
                             u16* __restrict__ Qo, u16* __restrict__ Ko, u16* __restrict__ Vto) {
  __shared__ float Vls[64][65];
  const int tid = threadIdx.x;
  const int t0 = blockIdx.x * 64, h = blockIdx.y, b = blockIdx.z;
  const int bh = b * 12 + h;
  const int num_special = nsp[0];
  const float QS = 0.125f * 1.4426950408889634f;  // D^-0.5 * log2e

#pragma unroll
  for (int s = 0; s < 2; ++s) {  // 0: q, 1: k
    const int base_col = s * 768 + h * 64;
    u16* outp = s ? Ko : Qo;
    const float qs = s ? 1.0f : QS;
#pragma unroll
    for (int i = 0; i < 8; ++i) {
      int pid = i * 256 + tid;
      int t = pid >> 5, dp = pid & 31;
      int n = t0 + t;
      size_t m = (size_t)b * 2048 + n;
      float x1 = bf2f(qkvb[m * 2304 + base_col + dp]);
      float x2 = bf2f(qkvb[m * 2304 + base_col + dp + 32]);
      float o1, o2;
      if (n < num_special) {
        o1 = x1; o2 = x2;
      } else {
        int ns = n - num_special;
        float c1 = cosT[ns * 64 + dp],      s1 = sinT[ns * 64 + dp];
        float c2 = cosT[ns * 64 + dp + 32], s2 = sinT[ns * 64 + dp + 32];
        o1 = x1 * c1 - x2 * s1;
        o2 = x2 * c2 + x1 * s2;
      }
      size_t ob = ((size_t)bh * 2048 + n) * 64;
      outp[ob + dp] = f2bf(o1 * qs);
      outp[ob + dp + 32] = f2bf(o2 * qs);
    }
  }
#pragma unroll
  for (int i = 0; i < 16; ++i) {
    int e = i * 256 + tid, t = e >> 6, d = e & 63;
    size_t m = (size_t)b * 2048 + t0 + t;
    Vls[t][d] = bf2f(qkvb[m * 2304 + 1536 + h * 64 + d]);
  }
  __syncthreads();
#pragma unroll
  for (int i = 0; i < 16; ++i) {
    int e = i * 256 + tid, d = e >> 6, t = e & 63;
    Vto[((size_t)bh * 64 + d) * 2048 + t0 + t] = f2bf(Vls[t][d]);
  }
}

// ---------------- flash attention: wave-owns-keys, read-once LDS -------------------
// 1D grid 1536 = qt*48 + bh (XCD-local K/V). 4 waves; wave owns keys
// [wave*16, wave*16+16) of each 64-key tile; Q (64x64) fully hoisted to registers
// (8 B-frags). Per kt per wave: 2 ds_read_b128 (K) + 4 ds_read_b64 (V) — K/V LDS
// traffic is read-once instead of 4x-replicated (R7 was LDS-issue-bound).
// S^T = MFMA(A=K_own, B=Q): lane holds S^T[key=quad*4+r][q=m*16+l16]; exp'd values
// are directly the PV A-frag. Per-wave partial O (64 f32/lane) is reduced across
// waves through LDS in a 4-round epilogue. No-max softmax (|log2-scores| < ~10).
__global__ __launch_bounds__(256, 3)
void attn(const u16* __restrict__ Q, const u16* __restrict__ Kg,
          const u16* __restrict__ Vt, u16* __restrict__ Out) {
  __shared__ u16 smem[2 * 64 * 72];   // 18432 B: [Ks | Vs]; Qs overlays Ks
  __shared__ float invS[64];
  u16* Ks = smem;
  u16* Vs = smem + 64 * 72;
  u16* Qs = smem;
  const int tid = threadIdx.x;
  const int wave = tid >> 6, lane = tid & 63;
  const int quad = lane >> 4, l16 = lane & 15;
  const int idx = blockIdx.x;
  const int bh = idx % 48, qt = idx / 48;
  const int b = bh / 12, h = bh % 12;
  const u16* Qb = Q + (size_t)bh * 2048 * 64;
  const u16* Kb = Kg + (size_t)bh * 2048 * 64;
  const u16* Vb = Vt + (size_t)bh * 64 * 2048;
  const int wkey0 = wave * 16;

  // stage Q tile (overlay Ks), hoist ALL Q B-frags (32 VGPRs)
#pragma unroll
  for (int j = 0; j < 2; ++j) {
    int c = j * 256 + tid;
    int row = c >> 3, kq = c & 7;
    *(U128*)&Qs[row * 72 + kq * 8] =
        *(const U128*)(Qb + (size_t)(qt * 64 + row) * 64 + kq * 8);
  }
  __syncthreads();
  bf16x8 qf[4][2];
#pragma unroll
  for (int m = 0; m < 4; ++m) {
    qf[m][0] = ldfrag(&Qs[(m * 16 + l16) * 72 + quad * 8]);
    qf[m][1] = ldfrag(&Qs[(m * 16 + l16) * 72 + quad * 8 + 32]);
  }

  f32x4 oacc[4][4];  // [q-block m][d-block db], partial over this wave's keys
#pragma unroll
  for (int m = 0; m < 4; ++m)
#pragma unroll
    for (int db = 0; db < 4; ++db) oacc[m][db] = (f32x4){0.f, 0.f, 0.f, 0.f};
  float psum[4] = {0.f, 0.f, 0.f, 0.f};  // partial softmax denom, q=m*16+l16

  for (int kt = 0; kt < 32; ++kt) {
    __syncthreads();
#pragma unroll
    for (int j = 0; j < 2; ++j) {
      int c = j * 256 + tid;
      int row = c >> 3, kq = c & 7;
      *(U128*)&Ks[row * 72 + kq * 8] =
          *(const U128*)(Kb + (size_t)(kt * 64 + row) * 64 + kq * 8);
      *(U128*)&Vs[row * 72 + kq * 8] =
          *(const U128*)(Vb + (size_t)row * 2048 + kt * 64 + kq * 8);
    }
    __syncthreads();

    // this wave's K A-frags (its 16 keys)
    bf16x8 ka0 = ldfrag(&Ks[(wkey0 + l16) * 72 + quad * 8]);
    bf16x8 ka1 = ldfrag(&Ks[(wkey0 + l16) * 72 + quad * 8 + 32]);

    // S^T per q-block; exp2; pack to PV A-frags
    s16x4 pf[4];
#pragma unroll
    for (int m = 0; m < 4; ++m) {
      f32x4 st = (f32x4){0.f, 0.f, 0.f, 0.f};
      st = __builtin_amdgcn_mfma_f32_16x16x32_bf16(ka0, qf[m][0], st, 0, 0, 0);
      st = __builtin_amdgcn_mfma_f32_16x16x32_bf16(ka1, qf[m][1], st, 0, 0, 0);
      float p0 = EXP2(st[0]);
      float p1 = EXP2(st[1]);
      float p2 = EXP2(st[2]);
      float p3 = EXP2(st[3]);
      psum[m] += (p0 + p1) + (p2 + p3);
      U64v pd;
      pd.x = pkbf(p0, p1);
      pd.y = pkbf(p2, p3);
      pf[m] = __builtin_bit_cast(s16x4, pd);
    }

    // O_partial += P V over this wave's keys
#pragma unroll
    for (int db = 0; db < 4; ++db) {
      s16x4 vf = __builtin_bit_cast(s16x4,
          *(const U64v*)&Vs[(db * 16 + l16) * 72 + wkey0 + quad * 4]);
#pragma unroll
      for (int m = 0; m < 4; ++m)
        oacc[m][db] = __builtin_amdgcn_mfma_f32_16x16x16bf16_1k(pf[m], vf, oacc[m][db], 0, 0, 0);
    }
  }

  // ---- epilogue: cross-wave reductions ----
#pragma unroll
  for (int m = 0; m < 4; ++m) {
    psum[m] += __shfl_xor(psum[m], 16, 64);
    psum[m] += __shfl_xor(psum[m], 32, 64);
  }
  __syncthreads();                 // last kt frag reads done; smem reusable
  float* LS = (float*)smem;        // [wave][64 q]
  if (quad == 0) {
#pragma unroll
    for (int m = 0; m < 4; ++m) LS[wave * 64 + m * 16 + l16] = psum[m];
  }
  __syncthreads();
  if (tid < 64) {
    float tot = LS[tid] + LS[64 + tid] + LS[128 + tid] + LS[192 + tid];
    invS[tid] = 1.0f / tot;
  }

  // O reduction: 4 rounds over d-blocks; OR[w][q][d] with 18-word q-stride
  float* OR = (float*)smem;        // 4*64*18*4 B = 18432 B exactly
  const int q = tid >> 2;
  const int d0 = (tid & 3) * 4;
  const size_t obase = ((size_t)(b * 2048 + qt * 64 + q)) * 768 + h * 64 + d0;
#pragma unroll
  for (int db = 0; db < 4; ++db) {
    __syncthreads();               // invS/LS reads done (db=0) / prior reads done
#pragma unroll
    for (int m = 0; m < 4; ++m)
#pragma unroll
      for (int r = 0; r < 4; ++r)
        OR[(wave * 64 + m * 16 + quad * 4 + r) * 18 + l16] = oacc[m][db][r];
    __syncthreads();
    float s0 = 0.f, s1 = 0.f, s2 = 0.f, s3 = 0.f;
#pragma unroll
    for (int w = 0; w < 4; ++w) {
      const float* p = &OR[(w * 64 + q) * 18 + d0];
      s0 += p[0]; s1 += p[1]; s2 += p[2]; s3 += p[3];
    }
    float iv = invS[q];
    U64v o;
    o.x = (uint32_t)f2bf(s0 * iv) | ((uint32_t)f2bf(s1 * iv) << 16);
    o.y = (uint32_t)f2bf(s2 * iv) | ((uint32_t)f2bf(s3 * iv) << 16);
    *(U64v*)&Out[obase + db * 16] = o;
  }
}

extern "C" void kernel_launch(void* const* d_in, const int* in_sizes, int n_in,
                              void* d_out, int out_size, void* d_ws, size_t ws_size,
                              hipStream_t stream) {
  (void)in_sizes; (void)n_in; (void)out_size; (void)ws_size;
  const float* x        = (const float*)d_in[0];
  const float* rope_cos = (const float*)d_in[1];
  const float* rope_sin = (const float*)d_in[2];
  const float* W_qkv    = (const float*)d_in[3];
  const float* b_qkv    = (const float*)d_in[4];
  const float* W_proj   = (const float*)d_in[5];
  const float* b_proj   = (const float*)d_in[6];
  const int*   nsp      = (const int*)d_in[7];
  float* out = (float*)d_out;

  char* ws = (char*)d_ws;
  u16* Xb   = (u16*)(ws);
  u16* Wqkt = (u16*)(ws + 12582912);
  u16* Wpt  = (u16*)(ws + 16121856);
  u16* qkvb = (u16*)(ws + 17301504);
  u16* Qb   = (u16*)(ws + 55050240);
  u16* Kb   = (u16*)(ws + 67633152);
  u16* Vtb  = (u16*)(ws + 80216064);
  u16* att  = (u16*)(ws + 92798976);

  cvt_f32_bf16<<<6144, 256, 0, stream>>>(x, Xb);
  transpose_cvt<<<dim3(72, 24), 256, 0, stream>>>(W_qkv, Wqkt, 768, 2304);
  transpose_cvt<<<dim3(24, 24), 256, 0, stream>>>(W_proj, Wpt, 768, 768);
  gemm_bt<1><<<dim3(18, 64), 256, 0, stream>>>(Xb, Wqkt, b_qkv, qkvb, 8192, 2304, 768);
  rope_scatter<<<dim3(32, 12, 4), 256, 0, stream>>>(qkvb, rope_cos, rope_sin, nsp, Qb, Kb, Vtb);
  attn<<<1536, 256, 0, stream>>>(Qb, Kb, Vtb, att);
  gemm_bt<0><<<dim3(6, 64), 256, 0, stream>>>(att, Wpt, b_proj, out, 8192, 768, 768);
}

// Round 9
// 249.277 us; speedup vs baseline: 1.5983x; 1.0412x over previous
//
#include <hip/hip_runtime.h>
#include <stdint.h>

typedef unsigned short u16;
typedef __bf16 bf16x8 __attribute__((ext_vector_type(8)));
typedef short s16x4 __attribute__((ext_vector_type(4)));
typedef float f32x4 __attribute__((ext_vector_type(4)));

typedef __attribute__((address_space(1))) void gvoid_t;
typedef __attribute__((address_space(3))) void lvoid_t;

struct alignas(16) U128 { uint32_t x, y, z, w; };
struct alignas(16) F128 { float x, y, z, w; };
struct alignas(8)  U64v { uint32_t x, y; };

__device__ __forceinline__ void gld16(const u16* g, u16* lds) {
  __builtin_amdgcn_global_load_lds((gvoid_t*)const_cast<u16*>(g),
                                   (lvoid_t*)lds, 16, 0, 0);
}

__device__ __forceinline__ u16 f2bf(float f) {
  uint32_t u = __builtin_bit_cast(uint32_t, f);
  u += 0x7FFFu + ((u >> 16) & 1u);   // RNE
  return (u16)(u >> 16);
}
__device__ __forceinline__ float bf2f(u16 h) {
  return __builtin_bit_cast(float, (uint32_t)h << 16);
}
__device__ __forceinline__ bf16x8 ldfrag(const u16* p) {
  U128 u = *reinterpret_cast<const U128*>(p);
  return __builtin_bit_cast(bf16x8, u);
}
// pack two f32 -> bf16x2 dword, round-half-up (values >= 0)
__device__ __forceinline__ uint32_t pkbf(float a, float b) {
  uint32_t ua = __builtin_bit_cast(uint32_t, a) + 0x8000u;
  uint32_t ub = __builtin_bit_cast(uint32_t, b) + 0x8000u;
  return (ua >> 16) | (ub & 0xFFFF0000u);
}

// raw v_exp_f32 (exp2) — scores bounded (|s|<~10), no denormal concerns
__device__ __forceinline__ float EXP2(float x) { return __builtin_amdgcn_exp2f(x); }

// ---------------- fp32 -> bf16 convert (x) ----------------
__global__ void cvt_f32_bf16(const float* __restrict__ in, u16* __restrict__ out) {
  int i = (blockIdx.x * 256 + threadIdx.x) * 4;
  F128 v = *reinterpret_cast<const F128*>(in + i);
  U64v o;
  o.x = (uint32_t)f2bf(v.x) | ((uint32_t)f2bf(v.y) << 16);
  o.y = (uint32_t)f2bf(v.z) | ((uint32_t)f2bf(v.w) << 16);
  *reinterpret_cast<U64v*>(out + i) = o;
}

// ---------------- transpose + convert weights: W (K x N f32) -> Wt (N x K bf16) ----
__global__ void transpose_cvt(const float* __restrict__ W, u16* __restrict__ Wt,
                              int K, int N) {
  __shared__ float T[32][33];
  const int n0 = blockIdx.x * 32, k0 = blockIdx.y * 32;
  const int tid = threadIdx.x;
#pragma unroll
  for (int i = 0; i < 4; ++i) {
    int e = i * 256 + tid, r = e >> 5, c = e & 31;
    T[r][c] = W[(size_t)(k0 + r) * N + n0 + c];
  }
  __syncthreads();
#pragma unroll
  for (int i = 0; i < 4; ++i) {
    int e = i * 256 + tid, r = e >> 5, c = e & 31;
    Wt[(size_t)(n0 + r) * K + k0 + c] = f2bf(T[c][r]);
  }
}

// ---------------- proj GEMM: C[M,N] = A[M,K] * Bt[N,K]^T + bias (f32 out) -----------
__global__ __launch_bounds__(256, 2)
void gemm_bt(const u16* __restrict__ A, const u16* __restrict__ Bt,
             const float* __restrict__ bias, float* __restrict__ C,
             int M, int N, int K) {
  __shared__ u16 As[128 * 32];
  __shared__ u16 Bs[128 * 32];
  const int tid = threadIdx.x;
  const int wave = tid >> 6, lane = tid & 63;
  const int quad = lane >> 4, l16 = lane & 15;
  const int m0 = blockIdx.y * 128, n0 = blockIdx.x * 128;
  const int wr = (wave & 1) * 64, wc = (wave >> 1) * 64;

  f32x4 acc[4][4];
#pragma unroll
  for (int i = 0; i < 4; ++i)
#pragma unroll
    for (int j = 0; j < 4; ++j) acc[i][j] = (f32x4){0.f, 0.f, 0.f, 0.f};

  for (int k0 = 0; k0 < K; k0 += 32) {
    __syncthreads();
#pragma unroll
    for (int j = 0; j < 2; ++j) {
      int c = (wave * 2 + j) * 64 + lane;
      int row = c >> 2, kq = c & 3;
      gld16(A + (size_t)(m0 + row) * K + k0 + kq * 8, &As[(wave * 2 + j) * 512]);
      gld16(Bt + (size_t)(n0 + row) * K + k0 + kq * 8, &Bs[(wave * 2 + j) * 512]);
    }
    __syncthreads();
    bf16x8 af[4], bfr[4];
#pragma unroll
    for (int rb = 0; rb < 4; ++rb) af[rb] = ldfrag(&As[(wr + rb * 16 + l16) * 32 + quad * 8]);
#pragma unroll
    for (int cb = 0; cb < 4; ++cb) bfr[cb] = ldfrag(&Bs[(wc + cb * 16 + l16) * 32 + quad * 8]);
#pragma unroll
    for (int rb = 0; rb < 4; ++rb)
#pragma unroll
      for (int cb = 0; cb < 4; ++cb)
        acc[rb][cb] = __builtin_amdgcn_mfma_f32_16x16x32_bf16(af[rb], bfr[cb], acc[rb][cb], 0, 0, 0);
  }
#pragma unroll
  for (int cb = 0; cb < 4; ++cb) {
    int col = n0 + wc + cb * 16 + l16;
    float bv = bias[col];
#pragma unroll
    for (int rb = 0; rb < 4; ++rb) {
#pragma unroll
      for (int r = 0; r < 4; ++r) {
        int row = m0 + wr + rb * 16 + quad * 4 + r;
        C[(size_t)row * N + col] = acc[rb][cb][r] + bv;
      }
    }
  }
}

// ---------------- fused QKV GEMM + bias + RoPE + scatter ----------------------------
// C = X(8192x768) * Wqkt(2304x768)^T; blockIdx.x: 0-5 Q, 6-11 K, 12-17 V (N-sections
// 768-aligned, 128 | 768). Each wave's 64-col span == one head (wc in {0,64}).
// RoPE pair (d, d+32) lives in accumulator blocks (cb, cb+2) of the SAME lane.
// Q gets D^-0.5*log2e folded in (attn softmax runs in log2 domain).
// Q,K -> (B*H, N, D) bf16; V -> transposed (B*H, D, N) bf16 (4 tokens per 8B store).
__global__ __launch_bounds__(256, 2)
void gemm_qkv_rope(const u16* __restrict__ A, const u16* __restrict__ Bt,
                   const float* __restrict__ bias,
                   const float* __restrict__ cosT, const float* __restrict__ sinT,
                   const int* __restrict__ nsp,
                   u16* __restrict__ Qo, u16* __restrict__ Ko, u16* __restrict__ Vto) {
  __shared__ u16 As[128 * 32];
  __shared__ u16 Bs[128 * 32];
  const int K = 768, N = 2304;
  const int tid = threadIdx.x;
  const int wave = tid >> 6, lane = tid & 63;
  const int quad = lane >> 4, l16 = lane & 15;
  const int m0 = blockIdx.y * 128, n0 = blockIdx.x * 128;
  const int wr = (wave & 1) * 64, wc = (wave >> 1) * 64;

  f32x4 acc[4][4];
#pragma unroll
  for (int i = 0; i < 4; ++i)
#pragma unroll
    for (int j = 0; j < 4; ++j) acc[i][j] = (f32x4){0.f, 0.f, 0.f, 0.f};

  for (int k0 = 0; k0 < K; k0 += 32) {
    __syncthreads();
#pragma unroll
    for (int j = 0; j < 2; ++j) {
      int c = (wave * 2 + j) * 64 + lane;
      int row = c >> 2, kq = c & 3;
      gld16(A + (size_t)(m0 + row) * K + k0 + kq * 8, &As[(wave * 2 + j) * 512]);
      gld16(Bt + (size_t)(n0 + row) * K + k0 + kq * 8, &Bs[(wave * 2 + j) * 512]);
    }
    __syncthreads();
    bf16x8 af[4], bfr[4];
#pragma unroll
    for (int rb = 0; rb < 4; ++rb) af[rb] = ldfrag(&As[(wr + rb * 16 + l16) * 32 + quad * 8]);
#pragma unroll
    for (int cb = 0; cb < 4; ++cb) bfr[cb] = ldfrag(&Bs[(wc + cb * 16 + l16) * 32 + quad * 8]);
#pragma unroll
    for (int rb = 0; rb < 4; ++rb)
#pragma unroll
      for (int cb = 0; cb < 4; ++cb)
        acc[rb][cb] = __builtin_amdgcn_mfma_f32_16x16x32_bf16(af[rb], bfr[cb], acc[rb][cb], 0, 0, 0);
  }

  // ---- fused epilogue ----
  const int sec = blockIdx.x / 6;          // 0=Q, 1=K, 2=V
  const int gcol0 = n0 + wc;               // 64-aligned: one head per wave
  const int hh = (gcol0 >> 6) % 12;
  const int bb = m0 >> 11;                 // 2048 % 128 == 0: one batch per block
  const int nbase = m0 & 2047;
  const int bh = bb * 12 + hh;
  const int num_special = nsp[0];
  const float QS = 0.125f * 1.4426950408889634f;  // D^-0.5 * log2e

  if (sec < 2) {
    u16* outp = sec ? Ko : Qo;
    const float qs = sec ? 1.0f : QS;
#pragma unroll
    for (int cbp = 0; cbp < 2; ++cbp) {
      const int d1 = cbp * 16 + l16;       // 0..31
      const int d2 = d1 + 32;
      const float bv1 = bias[gcol0 + d1];
      const float bv2 = bias[gcol0 + d2];
#pragma unroll
      for (int rb = 0; rb < 4; ++rb) {
#pragma unroll
        for (int r = 0; r < 4; ++r) {
          const int n = nbase + wr + rb * 16 + quad * 4 + r;
          float v1 = acc[rb][cbp][r] + bv1;
          float v2 = acc[rb][cbp + 2][r] + bv2;
          float o1, o2;
          if (n < num_special) {
            o1 = v1; o2 = v2;
          } else {
            int ns = n - num_special;
            float c1 = cosT[ns * 64 + d1], s1 = sinT[ns * 64 + d1];
            float c2 = cosT[ns * 64 + d2], s2 = sinT[ns * 64 + d2];
            o1 = v1 * c1 - v2 * s1;
            o2 = v2 * c2 + v1 * s2;
          }
          size_t ob = ((size_t)bh * 2048 + n) * 64;
          outp[ob + d1] = f2bf(o1 * qs);
          outp[ob + d2] = f2bf(o2 * qs);
        }
      }
    }
  } else {
    // V: bias + transposed write (d-major), 4 consecutive tokens per 8B store
#pragma unroll
    for (int cb = 0; cb < 4; ++cb) {
      const int d = cb * 16 + l16;
      const float bv = bias[gcol0 + d];
#pragma unroll
      for (int rb = 0; rb < 4; ++rb) {
        const int nr = nbase + wr + rb * 16 + quad * 4;
        U64v o;
        o.x = (uint32_t)f2bf(acc[rb][cb][0] + bv) |
              ((uint32_t)f2bf(acc[rb][cb][1] + bv) << 16);
        o.y = (uint32_t)f2bf(acc[rb][cb][2] + bv) |
              ((uint32_t)f2bf(acc[rb][cb][3] + bv) << 16);
        *(U64v*)&Vto[((size_t)bh * 64 + d) * 2048 + nr] = o;
      }
    }
  }
}

// ---------------- flash attention: wave-owns-keys, read-once LDS -------------------
// 1D grid 1536 = qt*48 + bh (XCD-local K/V). 4 waves; wave owns keys
// [wave*16, wave*16+16) of each 64-key tile; Q (64x64) fully hoisted to registers
// (8 B-frags). Per kt per wave: 2 ds_read_b128 (K) + 4 ds_read_b64 (V).
// S^T = MFMA(A=K_own, B=Q): lane holds S^T[key=quad*4+r][q=m*16+l16]; exp'd values
// are directly the PV A-frag. Per-wave partial O reduced across waves through LDS.
// No-max softmax (|log2-scores| < ~10).
__global__ __launch_bounds__(256, 3)
void attn(const u16* __restrict__ Q, const u16* __restrict__ Kg,
          const u16* __restrict__ Vt, u16* __restrict__ Out) {
  __shared__ u16 smem[2 * 64 * 72];   // 18432 B: [Ks | Vs]; Qs overlays Ks
  __shared__ float invS[64];
  u16* Ks = smem;
  u16* Vs = smem + 64 * 72;
  u16* Qs = smem;
  const int tid = threadIdx.x;
  const int wave = tid >> 6, lane = tid & 63;
  const int quad = lane >> 4, l16 = lane & 15;
  const int idx = blockIdx.x;
  const int bh = idx % 48, qt = idx / 48;
  const int b = bh / 12, h = bh % 12;
  const u16* Qb = Q + (size_t)bh * 2048 * 64;
  const u16* Kb = Kg + (size_t)bh * 2048 * 64;
  const u16* Vb = Vt + (size_t)bh * 64 * 2048;
  const int wkey0 = wave * 16;

#pragma unroll
  for (int j = 0; j < 2; ++j) {
    int c = j * 256 + tid;
    int row = c >> 3, kq = c & 7;
    *(U128*)&Qs[row * 72 + kq * 8] =
        *(const U128*)(Qb + (size_t)(qt * 64 + row) * 64 + kq * 8);
  }
  __syncthreads();
  bf16x8 qf[4][2];
#pragma unroll
  for (int m = 0; m < 4; ++m) {
    qf[m][0] = ldfrag(&Qs[(m * 16 + l16) * 72 + quad * 8]);
    qf[m][1] = ldfrag(&Qs[(m * 16 + l16) * 72 + quad * 8 + 32]);
  }

  f32x4 oacc[4][4];  // [q-block m][d-block db], partial over this wave's keys
#pragma unroll
  for (int m = 0; m < 4; ++m)
#pragma unroll
    for (int db = 0; db < 4; ++db) oacc[m][db] = (f32x4){0.f, 0.f, 0.f, 0.f};
  float psum[4] = {0.f, 0.f, 0.f, 0.f};

  for (int kt = 0; kt < 32; ++kt) {
    __syncthreads();
#pragma unroll
    for (int j = 0; j < 2; ++j) {
      int c = j * 256 + tid;
      int row = c >> 3, kq = c & 7;
      *(U128*)&Ks[row * 72 + kq * 8] =
          *(const U128*)(Kb + (size_t)(kt * 64 + row) * 64 + kq * 8);
      *(U128*)&Vs[row * 72 + kq * 8] =
          *(const U128*)(Vb + (size_t)row * 2048 + kt * 64 + kq * 8);
    }
    __syncthreads();

    bf16x8 ka0 = ldfrag(&Ks[(wkey0 + l16) * 72 + quad * 8]);
    bf16x8 ka1 = ldfrag(&Ks[(wkey0 + l16) * 72 + quad * 8 + 32]);

    s16x4 pf[4];
#pragma unroll
    for (int m = 0; m < 4; ++m) {
      f32x4 st = (f32x4){0.f, 0.f, 0.f, 0.f};
      st = __builtin_amdgcn_mfma_f32_16x16x32_bf16(ka0, qf[m][0], st, 0, 0, 0);
      st = __builtin_amdgcn_mfma_f32_16x16x32_bf16(ka1, qf[m][1], st, 0, 0, 0);
      float p0 = EXP2(st[0]);
      float p1 = EXP2(st[1]);
      float p2 = EXP2(st[2]);
      float p3 = EXP2(st[3]);
      psum[m] += (p0 + p1) + (p2 + p3);
      U64v pd;
      pd.x = pkbf(p0, p1);
      pd.y = pkbf(p2, p3);
      pf[m] = __builtin_bit_cast(s16x4, pd);
    }

#pragma unroll
    for (int db = 0; db < 4; ++db) {
      s16x4 vf = __builtin_bit_cast(s16x4,
          *(const U64v*)&Vs[(db * 16 + l16) * 72 + wkey0 + quad * 4]);
#pragma unroll
      for (int m = 0; m < 4; ++m)
        oacc[m][db] = __builtin_amdgcn_mfma_f32_16x16x16bf16_1k(pf[m], vf, oacc[m][db], 0, 0, 0);
    }
  }

  // ---- epilogue: cross-wave reductions ----
#pragma unroll
  for (int m = 0; m < 4; ++m) {
    psum[m] += __shfl_xor(psum[m], 16, 64);
    psum[m] += __shfl_xor(psum[m], 32, 64);
  }
  __syncthreads();
  float* LS = (float*)smem;        // [wave][64 q]
  if (quad == 0) {
#pragma unroll
    for (int m = 0; m < 4; ++m) LS[wave * 64 + m * 16 + l16] = psum[m];
  }
  __syncthreads();
  if (tid < 64) {
    float tot = LS[tid] + LS[64 + tid] + LS[128 + tid] + LS[192 + tid];
    invS[tid] = 1.0f / tot;
  }

  float* OR = (float*)smem;        // 4*64*18*4 B = 18432 B exactly
  const int q = tid >> 2;
  const int d0 = (tid & 3) * 4;
  const size_t obase = ((size_t)(b * 2048 + qt * 64 + q)) * 768 + h * 64 + d0;
#pragma unroll
  for (int db = 0; db < 4; ++db) {
    __syncthreads();
#pragma unroll
    for (int m = 0; m < 4; ++m)
#pragma unroll
      for (int r = 0; r < 4; ++r)
        OR[(wave * 64 + m * 16 + quad * 4 + r) * 18 + l16] = oacc[m][db][r];
    __syncthreads();
    float s0 = 0.f, s1 = 0.f, s2 = 0.f, s3 = 0.f;
#pragma unroll
    for (int w = 0; w < 4; ++w) {
      const float* p = &OR[(w * 64 + q) * 18 + d0];
      s0 += p[0]; s1 += p[1]; s2 += p[2]; s3 += p[3];
    }
    float iv = invS[q];
    U64v o;
    o.x = (uint32_t)f2bf(s0 * iv) | ((uint32_t)f2bf(s1 * iv) << 16);
    o.y = (uint32_t)f2bf(s2 * iv) | ((uint32_t)f2bf(s3 * iv) << 16);
    *(U64v*)&Out[obase + db * 16] = o;
  }
}

extern "C" void kernel_launch(void* const* d_in, const int* in_sizes, int n_in,
                              void* d_out, int out_size, void* d_ws, size_t ws_size,
                              hipStream_t stream) {
  (void)in_sizes; (void)n_in; (void)out_size; (void)ws_size;
  const float* x        = (const float*)d_in[0];
  const float* rope_cos = (const float*)d_in[1];
  const float* rope_sin = (const float*)d_in[2];
  const float* W_qkv    = (const float*)d_in[3];
  const float* b_qkv    = (const float*)d_in[4];
  const float* W_proj   = (const float*)d_in[5];
  const float* b_proj   = (const float*)d_in[6];
  const int*   nsp      = (const int*)d_in[7];
  float* out = (float*)d_out;

  char* ws = (char*)d_ws;
  u16* Xb   = (u16*)(ws);              // 8192x768 bf16
  u16* Wqkt = (u16*)(ws + 12582912);   // 2304x768 bf16
  u16* Wpt  = (u16*)(ws + 16121856);   // 768x768 bf16
  u16* Qb   = (u16*)(ws + 55050240);   // 48x2048x64 bf16
  u16* Kb   = (u16*)(ws + 67633152);
  u16* Vtb  = (u16*)(ws + 80216064);   // 48x64x2048 bf16
  u16* att  = (u16*)(ws + 92798976);   // 8192x768 bf16

  cvt_f32_bf16<<<6144, 256, 0, stream>>>(x, Xb);
  transpose_cvt<<<dim3(72, 24), 256, 0, stream>>>(W_qkv, Wqkt, 768, 2304);
  transpose_cvt<<<dim3(24, 24), 256, 0, stream>>>(W_proj, Wpt, 768, 768);
  gemm_qkv_rope<<<dim3(18, 64), 256, 0, stream>>>(Xb, Wqkt, b_qkv, rope_cos, rope_sin,
                                                  nsp, Qb, Kb, Vtb);
  attn<<<1536, 256, 0, stream>>>(Qb, Kb, Vtb, att);
  gemm_bt<<<dim3(6, 64), 256, 0, stream>>>(att, Wpt, b_proj, out, 8192, 768, 768);
}